// Round 1
// baseline (1568.773 us; speedup 1.0000x reference)
//
#include <hip/hip_runtime.h>
#include <hip/hip_bf16.h>

#define HID 16
#define CLS 40
#define FIN 512

// ---------- degree / norm precompute ----------
__global__ __launch_bounds__(256) void deg_init_k(float* __restrict__ deg, int n) {
    int i = blockIdx.x * 256 + threadIdx.x;
    if (i < n) deg[i] = 1.0f;  // self-loop weight (fill_value=1.0)
}

__global__ __launch_bounds__(256) void deg_acc_k(const int* __restrict__ col,
                                                 const float* __restrict__ w,
                                                 float* __restrict__ deg, int E) {
    int e = blockIdx.x * 256 + threadIdx.x;
    if (e < E) atomicAdd(&deg[col[e]], w[e]);
}

__global__ __launch_bounds__(256) void dinv_k(float* __restrict__ deg, int n) {
    int i = blockIdx.x * 256 + threadIdx.x;
    if (i < n) { float d = deg[i]; deg[i] = d > 0.f ? rsqrtf(d) : 0.f; }
}

__global__ __launch_bounds__(256) void norm_k(const int* __restrict__ row,
                                              const int* __restrict__ col,
                                              const float* __restrict__ w,
                                              const float* __restrict__ dinv,
                                              float* __restrict__ norm, int E) {
    int e = blockIdx.x * 256 + threadIdx.x;
    if (e < E) norm[e] = dinv[row[e]] * w[e] * dinv[col[e]];
}

// ---------- h = x @ W1  (N x 512 @ 512 x 16) ----------
// thread-per-row; W1 staged in LDS, read at wave-uniform addresses (broadcast).
__global__ __launch_bounds__(256) void gemm1_k(const float* __restrict__ x,
                                               const float* __restrict__ W1,
                                               float* __restrict__ h, int n) {
    __shared__ float w1s[FIN * HID];
    {
        const float4* src = (const float4*)W1;
        float4* dst = (float4*)w1s;
        for (int i = threadIdx.x; i < FIN * HID / 4; i += 256) dst[i] = src[i];
    }
    __syncthreads();
    int r = blockIdx.x * 256 + threadIdx.x;
    if (r >= n) return;
    const float4* xr = (const float4*)(x + (size_t)r * FIN);
    float acc[HID];
#pragma unroll
    for (int c = 0; c < HID; ++c) acc[c] = 0.f;
    for (int q = 0; q < FIN / 4; ++q) {
        float4 xv = xr[q];
        const float* wk = &w1s[q * 4 * HID];
#pragma unroll
        for (int c = 0; c < HID; ++c)
            acc[c] += xv.x * wk[c] + xv.y * wk[HID + c] +
                      xv.z * wk[2 * HID + c] + xv.w * wk[3 * HID + c];
    }
    float4* hv = (float4*)(h + (size_t)r * HID);
#pragma unroll
    for (int q = 0; q < HID / 4; ++q)
        hv[q] = make_float4(acc[4 * q], acc[4 * q + 1], acc[4 * q + 2], acc[4 * q + 3]);
}

// ---------- aggregation: self-loop init  agg[i] = h[i] * dinv[i]^2 ----------
__global__ __launch_bounds__(256) void agg_init_k(const float* __restrict__ h,
                                                  const float* __restrict__ dinv,
                                                  float* __restrict__ agg, int n) {
    int tid = blockIdx.x * 256 + threadIdx.x;
    int i = tid >> 4;
    if (i >= n) return;
    float di = dinv[i];
    agg[tid] = h[tid] * di * di;
}

// ---------- aggregation: edge scatter-add (thread per (edge, float4-chunk)) ----------
__global__ __launch_bounds__(256) void agg_edge_k(const float* __restrict__ h,
                                                  const int* __restrict__ row,
                                                  const int* __restrict__ col,
                                                  const float* __restrict__ norm,
                                                  float* __restrict__ agg, int E) {
    int tid = blockIdx.x * 256 + threadIdx.x;
    int e = tid >> 2;
    if (e >= E) return;
    int q = tid & 3;
    int r = row[e], c = col[e];
    float nm = norm[e];
    float4 hv = *(const float4*)(h + (size_t)r * HID + q * 4);
    float* ap = agg + (size_t)c * HID + q * 4;
    atomicAdd(ap + 0, hv.x * nm);
    atomicAdd(ap + 1, hv.y * nm);
    atomicAdd(ap + 2, hv.z * nm);
    atomicAdd(ap + 3, hv.w * nm);
}

// ---------- h1 = relu(agg1 + b1); also seed agg2 with self-loop ----------
__global__ __launch_bounds__(256) void relu_init_k(float* __restrict__ agg1,
                                                   const float* __restrict__ b1,
                                                   const float* __restrict__ dinv,
                                                   float* __restrict__ agg2, int n) {
    int tid = blockIdx.x * 256 + threadIdx.x;
    int i = tid >> 4;
    if (i >= n) return;
    int j = tid & 15;
    float v = fmaxf(agg1[tid] + b1[j], 0.f);
    agg1[tid] = v;  // becomes h1
    float di = dinv[i];
    agg2[tid] = v * di * di;
}

// ---------- out = log_softmax(agg2 @ W2 + b2) ----------
__global__ __launch_bounds__(256) void out_k(const float* __restrict__ agg2,
                                             const float* __restrict__ W2,
                                             const float* __restrict__ b2,
                                             float* __restrict__ out, int n) {
    __shared__ float w2s[HID * CLS];
    __shared__ float b2s[CLS];
    for (int i = threadIdx.x; i < HID * CLS; i += 256) w2s[i] = W2[i];
    if (threadIdx.x < CLS) b2s[threadIdx.x] = b2[threadIdx.x];
    __syncthreads();
    int i = blockIdx.x * 256 + threadIdx.x;
    if (i >= n) return;
    float a[HID];
    const float4* av = (const float4*)(agg2 + (size_t)i * HID);
#pragma unroll
    for (int q = 0; q < HID / 4; ++q) {
        float4 v = av[q];
        a[4 * q] = v.x; a[4 * q + 1] = v.y; a[4 * q + 2] = v.z; a[4 * q + 3] = v.w;
    }
    float z[CLS];
#pragma unroll
    for (int c = 0; c < CLS; ++c) z[c] = b2s[c];
#pragma unroll
    for (int k = 0; k < HID; ++k) {
        float ak = a[k];
#pragma unroll
        for (int c = 0; c < CLS; ++c) z[c] += ak * w2s[k * CLS + c];
    }
    float m = z[0];
#pragma unroll
    for (int c = 1; c < CLS; ++c) m = fmaxf(m, z[c]);
    float s = 0.f;
#pragma unroll
    for (int c = 0; c < CLS; ++c) s += expf(z[c] - m);
    float l = logf(s);
    float* o = out + (size_t)i * CLS;
#pragma unroll
    for (int c = 0; c < CLS; ++c) o[c] = z[c] - m - l;
}

extern "C" void kernel_launch(void* const* d_in, const int* in_sizes, int n_in,
                              void* d_out, int out_size, void* d_ws, size_t ws_size,
                              hipStream_t stream) {
    const float* x  = (const float*)d_in[0];
    const float* ew = (const float*)d_in[1];
    const float* W1 = (const float*)d_in[2];
    const float* b1 = (const float*)d_in[3];
    const float* W2 = (const float*)d_in[4];
    const float* b2 = (const float*)d_in[5];
    const int*   ei = (const int*)d_in[6];

    int n = in_sizes[0] / FIN;   // 100000
    int E = in_sizes[1];         // 3200000
    const int* row = ei;         // edge_index[0]
    const int* col = ei + E;     // edge_index[1]

    float* ws   = (float*)d_ws;
    float* deg  = ws;                         // n floats (becomes dinv in place)
    float* norm = ws + n;                     // E floats
    float* h    = norm + E;                   // n*HID floats
    float* agg1 = h + (size_t)n * HID;        // n*HID floats (becomes h1)
    float* agg2 = agg1 + (size_t)n * HID;     // n*HID floats
    float* outp = (float*)d_out;

    dim3 b(256);
    deg_init_k<<<(n + 255) / 256, b, 0, stream>>>(deg, n);
    deg_acc_k<<<(E + 255) / 256, b, 0, stream>>>(col, ew, deg, E);
    dinv_k<<<(n + 255) / 256, b, 0, stream>>>(deg, n);
    norm_k<<<(E + 255) / 256, b, 0, stream>>>(row, col, ew, deg, norm, E);

    gemm1_k<<<(n + 255) / 256, b, 0, stream>>>(x, W1, h, n);

    int nj = n * HID;
    agg_init_k<<<(nj + 255) / 256, b, 0, stream>>>(h, deg, agg1, n);
    long long et = (long long)E * 4;
    agg_edge_k<<<(unsigned)((et + 255) / 256), b, 0, stream>>>(h, row, col, norm, agg1, E);

    relu_init_k<<<(nj + 255) / 256, b, 0, stream>>>(agg1, b1, deg, agg2, n);
    agg_edge_k<<<(unsigned)((et + 255) / 256), b, 0, stream>>>(agg1, row, col, norm, agg2, E);

    out_k<<<(n + 255) / 256, b, 0, stream>>>(agg2, W2, b2, outp, n);
}

// Round 2
// 618.333 us; speedup vs baseline: 2.5371x; 2.5371x over previous
//
#include <hip/hip_runtime.h>
#include <hip/hip_bf16.h>

#define HID 16
#define CLS 40
#define FIN 512

// ================= counting sort by col =================

__global__ __launch_bounds__(256) void hist_k(const int* __restrict__ col,
                                              int* __restrict__ cnt, int E) {
    int e = blockIdx.x * 256 + threadIdx.x;
    if (e < E) atomicAdd(&cnt[col[e]], 1);
}

// block sums over chunks of 1024 counts
__global__ __launch_bounds__(256) void scan1_k(const int* __restrict__ cnt,
                                               int* __restrict__ bsum, int n) {
    __shared__ int ws[4];
    int b = blockIdx.x, t = threadIdx.x;
    int i0 = b * 1024 + t * 4;
    int s = 0;
#pragma unroll
    for (int q = 0; q < 4; ++q) if (i0 + q < n) s += cnt[i0 + q];
    // wave reduce
    for (int d = 32; d > 0; d >>= 1) s += __shfl_xor(s, d);
    int lane = t & 63, wid = t >> 6;
    if (lane == 0) ws[wid] = s;
    __syncthreads();
    if (t == 0) bsum[b] = ws[0] + ws[1] + ws[2] + ws[3];
}

__global__ void scan2_k(int* __restrict__ bsum, int G) {
    if (blockIdx.x == 0 && threadIdx.x == 0) {
        int run = 0;
        for (int b = 0; b < G; ++b) { int t = bsum[b]; bsum[b] = run; run += t; }
    }
}

__global__ __launch_bounds__(256) void scan3_k(const int* __restrict__ cnt,
                                               const int* __restrict__ bsum,
                                               int* __restrict__ off,
                                               int* __restrict__ cur, int n) {
    __shared__ int wsum[4];
    __shared__ int wbase[4];
    int b = blockIdx.x, t = threadIdx.x;
    int i0 = b * 1024 + t * 4;
    int c[4];
#pragma unroll
    for (int q = 0; q < 4; ++q) c[q] = (i0 + q < n) ? cnt[i0 + q] : 0;
    int s = c[0] + c[1] + c[2] + c[3];
    int lane = t & 63, wid = t >> 6;
    int v = s;
    for (int d = 1; d < 64; d <<= 1) { int u = __shfl_up(v, d); if (lane >= d) v += u; }
    if (lane == 63) wsum[wid] = v;
    __syncthreads();
    if (t == 0) { int r = 0; for (int q = 0; q < 4; ++q) { wbase[q] = r; r += wsum[q]; } }
    __syncthreads();
    int o = v - s + wbase[wid] + bsum[b];
#pragma unroll
    for (int q = 0; q < 4; ++q) {
        if (i0 + q < n) { off[i0 + q] = o; cur[i0 + q] = o; o += c[q]; }
    }
}

__global__ __launch_bounds__(256) void scatter_k(const int* __restrict__ row,
                                                 const int* __restrict__ col,
                                                 const float* __restrict__ w,
                                                 int* __restrict__ cur,
                                                 int* __restrict__ src,
                                                 float* __restrict__ wn, int E) {
    int e = blockIdx.x * 256 + threadIdx.x;
    if (e >= E) return;
    int c = col[e];
    int pos = atomicAdd(&cur[c], 1);
    src[pos] = row[e];
    wn[pos] = w[e];
}

// deg[i] = 1 + sum(w over segment); dinv = rsqrt
__global__ __launch_bounds__(256) void dinv_k(const int* __restrict__ off,
                                              const int* __restrict__ cnt,
                                              const float* __restrict__ wn,
                                              float* __restrict__ dinv, int n) {
    int i = blockIdx.x * 256 + threadIdx.x;
    if (i >= n) return;
    int s = off[i], e = s + cnt[i];
    float d = 1.0f;
    for (int p = s; p < e; ++p) d += wn[p];
    dinv[i] = rsqrtf(d);
}

// wn[p] <- dinv[dest] * w[p] * dinv[src[p]]  (16-lane group per node)
__global__ __launch_bounds__(256) void norm_k(const int* __restrict__ off,
                                              const int* __restrict__ cnt,
                                              const int* __restrict__ src,
                                              const float* __restrict__ dinv,
                                              float* __restrict__ wn, int n) {
    int tid = blockIdx.x * 256 + threadIdx.x;
    int i = tid >> 4;
    if (i >= n) return;
    int lane = tid & 15;
    int s = off[i], e = s + cnt[i];
    float di = dinv[i];
    for (int p = s + lane; p < e; p += 16)
        wn[p] = di * wn[p] * dinv[src[p]];
}

// ================= h = x @ W1 =================
__global__ __launch_bounds__(256) void gemm1_k(const float* __restrict__ x,
                                               const float* __restrict__ W1,
                                               float* __restrict__ h, int n) {
    __shared__ float w1s[FIN * HID];
    {
        const float4* s4 = (const float4*)W1;
        float4* d4 = (float4*)w1s;
        for (int i = threadIdx.x; i < FIN * HID / 4; i += 256) d4[i] = s4[i];
    }
    __syncthreads();
    int r = blockIdx.x * 256 + threadIdx.x;
    if (r >= n) return;
    const float4* xr = (const float4*)(x + (size_t)r * FIN);
    float acc[HID];
#pragma unroll
    for (int c = 0; c < HID; ++c) acc[c] = 0.f;
    for (int q = 0; q < FIN / 4; ++q) {
        float4 xv = xr[q];
        const float* wk = &w1s[q * 4 * HID];
#pragma unroll
        for (int c = 0; c < HID; ++c)
            acc[c] += xv.x * wk[c] + xv.y * wk[HID + c] +
                      xv.z * wk[2 * HID + c] + xv.w * wk[3 * HID + c];
    }
    float4* hv = (float4*)(h + (size_t)r * HID);
#pragma unroll
    for (int q = 0; q < HID / 4; ++q)
        hv[q] = make_float4(acc[4 * q], acc[4 * q + 1], acc[4 * q + 2], acc[4 * q + 3]);
}

// ================= gather aggregation (no atomics) =================
// out[i][j] = dinv_i^2 * hin[i][j] + sum_p wn[p] * hin[src[p]][j]
__global__ __launch_bounds__(256) void agg_gather_k(const float* __restrict__ hin,
                                                    const float* __restrict__ dinv,
                                                    const int* __restrict__ off,
                                                    const int* __restrict__ cnt,
                                                    const int* __restrict__ src,
                                                    const float* __restrict__ wn,
                                                    float* __restrict__ out, int n) {
    int tid = blockIdx.x * 256 + threadIdx.x;
    int i = tid >> 4;
    if (i >= n) return;
    int lane = tid & 15;
    float di = dinv[i];
    float acc0 = di * di * hin[(size_t)i * HID + lane];
    float acc1 = 0.f;
    int p = off[i], e = p + cnt[i];
    for (; p + 1 < e; p += 2) {
        int r0 = src[p], r1 = src[p + 1];
        float w0 = wn[p], w1 = wn[p + 1];
        acc0 += w0 * hin[(size_t)r0 * HID + lane];
        acc1 += w1 * hin[(size_t)r1 * HID + lane];
    }
    if (p < e) acc0 += wn[p] * hin[(size_t)src[p] * HID + lane];
    out[(size_t)i * HID + lane] = acc0 + acc1;
}

// h1 = relu(agg1 + b1)
__global__ __launch_bounds__(256) void relu_k(const float* __restrict__ agg1,
                                              const float* __restrict__ b1,
                                              float* __restrict__ h1, int n) {
    int tid = blockIdx.x * 256 + threadIdx.x;
    if (tid >= n * HID) return;
    h1[tid] = fmaxf(agg1[tid] + b1[tid & (HID - 1)], 0.f);
}

// out = log_softmax(agg2 @ W2 + b2)
__global__ __launch_bounds__(256) void out_k(const float* __restrict__ agg2,
                                             const float* __restrict__ W2,
                                             const float* __restrict__ b2,
                                             float* __restrict__ out, int n) {
    __shared__ float w2s[HID * CLS];
    __shared__ float b2s[CLS];
    for (int i = threadIdx.x; i < HID * CLS; i += 256) w2s[i] = W2[i];
    if (threadIdx.x < CLS) b2s[threadIdx.x] = b2[threadIdx.x];
    __syncthreads();
    int i = blockIdx.x * 256 + threadIdx.x;
    if (i >= n) return;
    float a[HID];
    const float4* av = (const float4*)(agg2 + (size_t)i * HID);
#pragma unroll
    for (int q = 0; q < HID / 4; ++q) {
        float4 v = av[q];
        a[4 * q] = v.x; a[4 * q + 1] = v.y; a[4 * q + 2] = v.z; a[4 * q + 3] = v.w;
    }
    float z[CLS];
#pragma unroll
    for (int c = 0; c < CLS; ++c) z[c] = b2s[c];
#pragma unroll
    for (int k = 0; k < HID; ++k) {
        float ak = a[k];
#pragma unroll
        for (int c = 0; c < CLS; ++c) z[c] += ak * w2s[k * CLS + c];
    }
    float m = z[0];
#pragma unroll
    for (int c = 1; c < CLS; ++c) m = fmaxf(m, z[c]);
    float s = 0.f;
#pragma unroll
    for (int c = 0; c < CLS; ++c) s += expf(z[c] - m);
    float l = logf(s);
    float* o = out + (size_t)i * CLS;
#pragma unroll
    for (int c = 0; c < CLS; ++c) o[c] = z[c] - m - l;
}

extern "C" void kernel_launch(void* const* d_in, const int* in_sizes, int n_in,
                              void* d_out, int out_size, void* d_ws, size_t ws_size,
                              hipStream_t stream) {
    const float* x  = (const float*)d_in[0];
    const float* ew = (const float*)d_in[1];
    const float* W1 = (const float*)d_in[2];
    const float* b1 = (const float*)d_in[3];
    const float* W2 = (const float*)d_in[4];
    const float* b2 = (const float*)d_in[5];
    const int*   ei = (const int*)d_in[6];

    int n = in_sizes[0] / FIN;   // 100000
    int E = in_sizes[1];         // 3200000
    const int* row = ei;
    const int* col = ei + E;

    // workspace layout (all 4B elements)
    int*   cnt  = (int*)d_ws;                  // n
    int*   off  = cnt + n;                     // n
    int*   cur  = off + n;                     // n
    int*   bsum = cur + n;                     // 1024 (pad)
    float* dinv = (float*)(bsum + 1024);       // n
    int*   src  = (int*)(dinv + n);            // E
    float* wn   = (float*)(src + E);           // E
    float* h    = wn + E;                      // 16n
    float* agg1 = h + (size_t)16 * n;          // 16n
    float* agg2 = agg1 + (size_t)16 * n;       // 16n
    float* outp = (float*)d_out;

    int G = (n + 1023) / 1024;
    dim3 b(256);

    hipMemsetAsync(cnt, 0, (size_t)n * 4, stream);
    hist_k<<<(E + 255) / 256, b, 0, stream>>>(col, cnt, E);
    scan1_k<<<G, b, 0, stream>>>(cnt, bsum, n);
    scan2_k<<<1, 64, 0, stream>>>(bsum, G);
    scan3_k<<<G, b, 0, stream>>>(cnt, bsum, off, cur, n);
    scatter_k<<<(E + 255) / 256, b, 0, stream>>>(row, col, ew, cur, src, wn, E);

    dinv_k<<<(n + 255) / 256, b, 0, stream>>>(off, cnt, wn, dinv, n);
    int gnodes16 = (n * HID + 255) / 256;
    norm_k<<<gnodes16, b, 0, stream>>>(off, cnt, src, dinv, wn, n);

    gemm1_k<<<(n + 255) / 256, b, 0, stream>>>(x, W1, h, n);

    agg_gather_k<<<gnodes16, b, 0, stream>>>(h, dinv, off, cnt, src, wn, agg1, n);
    relu_k<<<gnodes16, b, 0, stream>>>(agg1, b1, h, n);   // h reused as h1
    agg_gather_k<<<gnodes16, b, 0, stream>>>(h, dinv, off, cnt, src, wn, agg2, n);

    out_k<<<(n + 255) / 256, b, 0, stream>>>(agg2, W2, b2, outp, n);
}

// Round 3
// 476.982 us; speedup vs baseline: 3.2890x; 1.2963x over previous
//
#include <hip/hip_runtime.h>
#include <hip/hip_bf16.h>

#define HID 16
#define CLS 40
#define FIN 512

// ================= counting sort by col (rank -> scan -> place) =============

// rank[e] = arrival index among edges with same destination; cnt[c] = in-degree
__global__ __launch_bounds__(256) void rank_k(const int* __restrict__ col,
                                              int* __restrict__ cnt,
                                              int* __restrict__ rank, int E) {
    int e = blockIdx.x * 256 + threadIdx.x;
    if (e < E) rank[e] = atomicAdd(&cnt[col[e]], 1);
}

// block sums over chunks of 1024 counts
__global__ __launch_bounds__(256) void scan1_k(const int* __restrict__ cnt,
                                               int* __restrict__ bsum, int n) {
    __shared__ int ws[4];
    int b = blockIdx.x, t = threadIdx.x;
    int i0 = b * 1024 + t * 4;
    int s = 0;
#pragma unroll
    for (int q = 0; q < 4; ++q) if (i0 + q < n) s += cnt[i0 + q];
    for (int d = 32; d > 0; d >>= 1) s += __shfl_xor(s, d);
    int lane = t & 63, wid = t >> 6;
    if (lane == 0) ws[wid] = s;
    __syncthreads();
    if (t == 0) bsum[b] = ws[0] + ws[1] + ws[2] + ws[3];
}

__global__ void scan2_k(int* __restrict__ bsum, int G) {
    if (blockIdx.x == 0 && threadIdx.x == 0) {
        int run = 0;
        for (int b = 0; b < G; ++b) { int t = bsum[b]; bsum[b] = run; run += t; }
    }
}

__global__ __launch_bounds__(256) void scan3_k(const int* __restrict__ cnt,
                                               const int* __restrict__ bsum,
                                               int* __restrict__ off, int n) {
    __shared__ int wsum[4];
    __shared__ int wbase[4];
    int b = blockIdx.x, t = threadIdx.x;
    int i0 = b * 1024 + t * 4;
    int c[4];
#pragma unroll
    for (int q = 0; q < 4; ++q) c[q] = (i0 + q < n) ? cnt[i0 + q] : 0;
    int s = c[0] + c[1] + c[2] + c[3];
    int lane = t & 63, wid = t >> 6;
    int v = s;
    for (int d = 1; d < 64; d <<= 1) { int u = __shfl_up(v, d); if (lane >= d) v += u; }
    if (lane == 63) wsum[wid] = v;
    __syncthreads();
    if (t == 0) { int r = 0; for (int q = 0; q < 4; ++q) { wbase[q] = r; r += wsum[q]; } }
    __syncthreads();
    int o = v - s + wbase[wid] + bsum[b];
#pragma unroll
    for (int q = 0; q < 4; ++q) {
        if (i0 + q < n) { off[i0 + q] = o; o += c[q]; }
    }
}

// single packed 8B store per edge, no atomic
__global__ __launch_bounds__(256) void place_k(const int* __restrict__ row,
                                               const int* __restrict__ col,
                                               const float* __restrict__ w,
                                               const int* __restrict__ off,
                                               const int* __restrict__ rank,
                                               int2* __restrict__ pair, int E) {
    int e = blockIdx.x * 256 + threadIdx.x;
    if (e >= E) return;
    int pos = off[col[e]] + rank[e];
    pair[pos] = make_int2(row[e], __float_as_int(w[e]));
}

// dinv[i] = rsqrt(1 + sum of raw w over segment)
__global__ __launch_bounds__(256) void dinv_k(const int* __restrict__ off,
                                              const int* __restrict__ cnt,
                                              const int2* __restrict__ pair,
                                              float* __restrict__ dinv, int n) {
    int i = blockIdx.x * 256 + threadIdx.x;
    if (i >= n) return;
    int s = off[i], e = s + cnt[i];
    float d = 1.0f;
    for (int p = s; p < e; ++p) d += __int_as_float(pair[p].y);
    dinv[i] = rsqrtf(d);
}

// pair[p].w <- dinv[dest] * w * dinv[src]  (16-lane group per node, coalesced)
__global__ __launch_bounds__(256) void norm_k(const int* __restrict__ off,
                                              const int* __restrict__ cnt,
                                              const float* __restrict__ dinv,
                                              int2* __restrict__ pair, int n) {
    int tid = blockIdx.x * 256 + threadIdx.x;
    int i = tid >> 4;
    if (i >= n) return;
    int lane = tid & 15;
    int s = off[i], e = s + cnt[i];
    float di = dinv[i];
    for (int p = s + lane; p < e; p += 16) {
        int2 pr = pair[p];
        pr.y = __float_as_int(di * __int_as_float(pr.y) * dinv[pr.x]);
        pair[p] = pr;
    }
}

// ================= h = x @ W1 =================
__global__ __launch_bounds__(256) void gemm1_k(const float* __restrict__ x,
                                               const float* __restrict__ W1,
                                               float* __restrict__ h, int n) {
    __shared__ float w1s[FIN * HID];
    {
        const float4* s4 = (const float4*)W1;
        float4* d4 = (float4*)w1s;
        for (int i = threadIdx.x; i < FIN * HID / 4; i += 256) d4[i] = s4[i];
    }
    __syncthreads();
    int r = blockIdx.x * 256 + threadIdx.x;
    if (r >= n) return;
    const float4* xr = (const float4*)(x + (size_t)r * FIN);
    float acc[HID];
#pragma unroll
    for (int c = 0; c < HID; ++c) acc[c] = 0.f;
    for (int q = 0; q < FIN / 4; ++q) {
        float4 xv = xr[q];
        const float* wk = &w1s[q * 4 * HID];
#pragma unroll
        for (int c = 0; c < HID; ++c)
            acc[c] += xv.x * wk[c] + xv.y * wk[HID + c] +
                      xv.z * wk[2 * HID + c] + xv.w * wk[3 * HID + c];
    }
    float4* hv = (float4*)(h + (size_t)r * HID);
#pragma unroll
    for (int q = 0; q < HID / 4; ++q)
        hv[q] = make_float4(acc[4 * q], acc[4 * q + 1], acc[4 * q + 2], acc[4 * q + 3]);
}

// ================= gather aggregation (no atomics) =================
// out[i][j] = dinv_i^2 * hin[i][j] + sum_p wn[p] * hin[src[p]][j]
// RELU=1: out = relu(out + b1)   (fused layer-1 epilogue)
template <int RELU>
__global__ __launch_bounds__(256) void agg_gather_k(const float* __restrict__ hin,
                                                    const float* __restrict__ dinv,
                                                    const int* __restrict__ off,
                                                    const int* __restrict__ cnt,
                                                    const int2* __restrict__ pair,
                                                    const float* __restrict__ b1,
                                                    float* __restrict__ out, int n) {
    int tid = blockIdx.x * 256 + threadIdx.x;
    int i = tid >> 4;
    if (i >= n) return;
    int lane = tid & 15;
    float di = dinv[i];
    float acc0 = di * di * hin[(size_t)i * HID + lane];
    float acc1 = 0.f, acc2 = 0.f, acc3 = 0.f;
    int p = off[i], e = p + cnt[i];
    for (; p + 3 < e; p += 4) {
        int2 a = pair[p], b = pair[p + 1], c = pair[p + 2], d = pair[p + 3];
        acc0 += __int_as_float(a.y) * hin[(size_t)a.x * HID + lane];
        acc1 += __int_as_float(b.y) * hin[(size_t)b.x * HID + lane];
        acc2 += __int_as_float(c.y) * hin[(size_t)c.x * HID + lane];
        acc3 += __int_as_float(d.y) * hin[(size_t)d.x * HID + lane];
    }
    for (; p < e; ++p) {
        int2 a = pair[p];
        acc0 += __int_as_float(a.y) * hin[(size_t)a.x * HID + lane];
    }
    float v = (acc0 + acc1) + (acc2 + acc3);
    if (RELU) v = fmaxf(v + b1[lane], 0.f);
    out[(size_t)i * HID + lane] = v;
}

// out = log_softmax(agg2 @ W2 + b2)
__global__ __launch_bounds__(256) void out_k(const float* __restrict__ agg2,
                                             const float* __restrict__ W2,
                                             const float* __restrict__ b2,
                                             float* __restrict__ out, int n) {
    __shared__ float w2s[HID * CLS];
    __shared__ float b2s[CLS];
    for (int i = threadIdx.x; i < HID * CLS; i += 256) w2s[i] = W2[i];
    if (threadIdx.x < CLS) b2s[threadIdx.x] = b2[threadIdx.x];
    __syncthreads();
    int i = blockIdx.x * 256 + threadIdx.x;
    if (i >= n) return;
    float a[HID];
    const float4* av = (const float4*)(agg2 + (size_t)i * HID);
#pragma unroll
    for (int q = 0; q < HID / 4; ++q) {
        float4 v = av[q];
        a[4 * q] = v.x; a[4 * q + 1] = v.y; a[4 * q + 2] = v.z; a[4 * q + 3] = v.w;
    }
    float z[CLS];
#pragma unroll
    for (int c = 0; c < CLS; ++c) z[c] = b2s[c];
#pragma unroll
    for (int k = 0; k < HID; ++k) {
        float ak = a[k];
#pragma unroll
        for (int c = 0; c < CLS; ++c) z[c] += ak * w2s[k * CLS + c];
    }
    float m = z[0];
#pragma unroll
    for (int c = 1; c < CLS; ++c) m = fmaxf(m, z[c]);
    float s = 0.f;
#pragma unroll
    for (int c = 0; c < CLS; ++c) s += __expf(z[c] - m);
    float l = __logf(s);
    float* o = out + (size_t)i * CLS;
#pragma unroll
    for (int c = 0; c < CLS; ++c) o[c] = z[c] - m - l;
}

extern "C" void kernel_launch(void* const* d_in, const int* in_sizes, int n_in,
                              void* d_out, int out_size, void* d_ws, size_t ws_size,
                              hipStream_t stream) {
    const float* x  = (const float*)d_in[0];
    const float* ew = (const float*)d_in[1];
    const float* W1 = (const float*)d_in[2];
    const float* b1 = (const float*)d_in[3];
    const float* W2 = (const float*)d_in[4];
    const float* b2 = (const float*)d_in[5];
    const int*   ei = (const int*)d_in[6];

    int n = in_sizes[0] / FIN;   // 100000
    int E = in_sizes[1];         // 3200000
    const int* row = ei;
    const int* col = ei + E;

    // workspace layout (4B units)
    int*   cnt  = (int*)d_ws;                    // n
    int*   off  = cnt + n;                       // n
    int*   bsum = off + n;                       // 1024
    float* dinv = (float*)(bsum + 1024);         // n
    int*   rank = (int*)(dinv + n);              // E
    int2*  pair = (int2*)(rank + E);             // E int2 (8B aligned: offset sums are even? ensure)
    float* h    = (float*)(pair + E);            // 16n
    float* h1   = h + (size_t)16 * n;            // 16n
    float* agg2 = h1 + (size_t)16 * n;           // 16n
    float* outp = (float*)d_out;

    int G = (n + 1023) / 1024;
    dim3 b(256);

    hipMemsetAsync(cnt, 0, (size_t)n * 4, stream);
    rank_k<<<(E + 255) / 256, b, 0, stream>>>(col, cnt, rank, E);
    scan1_k<<<G, b, 0, stream>>>(cnt, bsum, n);
    scan2_k<<<1, 64, 0, stream>>>(bsum, G);
    scan3_k<<<G, b, 0, stream>>>(cnt, bsum, off, n);
    place_k<<<(E + 255) / 256, b, 0, stream>>>(row, col, ew, off, rank, pair, E);

    dinv_k<<<(n + 255) / 256, b, 0, stream>>>(off, cnt, pair, dinv, n);
    int gnodes16 = (n * HID + 255) / 256;
    norm_k<<<gnodes16, b, 0, stream>>>(off, cnt, dinv, pair, n);

    gemm1_k<<<(n + 255) / 256, b, 0, stream>>>(x, W1, h, n);

    agg_gather_k<1><<<gnodes16, b, 0, stream>>>(h, dinv, off, cnt, pair, b1, h1, n);
    agg_gather_k<0><<<gnodes16, b, 0, stream>>>(h1, dinv, off, cnt, pair, b1, agg2, n);

    out_k<<<(n + 255) / 256, b, 0, stream>>>(agg2, W2, b2, outp, n);
}

// Round 4
// 367.295 us; speedup vs baseline: 4.2712x; 1.2986x over previous
//
#include <hip/hip_runtime.h>
#include <hip/hip_bf16.h>

#define HID 16
#define CLS 40
#define FIN 512
#define TILE 4000     // edges per bucketize block (LDS stage = 32KB + 8KB + ~10KB)
#define NBP 512       // padded bucket count; requires n <= 131072 (row fits 17 bits)

// ================= generic hierarchical exclusive scan (M ints) =============

__global__ __launch_bounds__(256) void scan1_k(const int* __restrict__ cnt,
                                               int* __restrict__ bsum, int M) {
    __shared__ int ws[4];
    int b = blockIdx.x, t = threadIdx.x;
    int i0 = b * 1024 + t * 4;
    int s = 0;
#pragma unroll
    for (int q = 0; q < 4; ++q) if (i0 + q < M) s += cnt[i0 + q];
    for (int d = 32; d > 0; d >>= 1) s += __shfl_xor(s, d);
    int lane = t & 63, wid = t >> 6;
    if (lane == 0) ws[wid] = s;
    __syncthreads();
    if (t == 0) bsum[b] = ws[0] + ws[1] + ws[2] + ws[3];
}

__global__ void scan2_k(int* __restrict__ bsum, int G) {
    if (blockIdx.x == 0 && threadIdx.x == 0) {
        int run = 0;
        for (int b = 0; b < G; ++b) { int t = bsum[b]; bsum[b] = run; run += t; }
    }
}

__global__ __launch_bounds__(256) void scan3_k(const int* __restrict__ cnt,
                                               const int* __restrict__ bsum,
                                               int* __restrict__ sout, int M) {
    __shared__ int wsum[4];
    __shared__ int wbase[4];
    int b = blockIdx.x, t = threadIdx.x;
    int i0 = b * 1024 + t * 4;
    int c[4];
#pragma unroll
    for (int q = 0; q < 4; ++q) c[q] = (i0 + q < M) ? cnt[i0 + q] : 0;
    int s = c[0] + c[1] + c[2] + c[3];
    int lane = t & 63, wid = t >> 6;
    int v = s;
    for (int d = 1; d < 64; d <<= 1) { int u = __shfl_up(v, d); if (lane >= d) v += u; }
    if (lane == 63) wsum[wid] = v;
    __syncthreads();
    if (t == 0) { int r = 0; for (int q = 0; q < 4; ++q) { wbase[q] = r; r += wsum[q]; } }
    __syncthreads();
    int o = v - s + wbase[wid] + bsum[b];
#pragma unroll
    for (int q = 0; q < 4; ++q) {
        if (i0 + q < M) { sout[i0 + q] = o; o += c[q]; }
    }
}

// ================= pass A: bucketize by col>>8 (LDS atomics only) ===========

// A1: per-(bucket, block) counts, stored bucket-major for the scan
__global__ __launch_bounds__(256) void bk_count_k(const int* __restrict__ col,
                                                  int* __restrict__ bcnt,
                                                  int E, int NB, int ABLK) {
    __shared__ int hist[NBP];
    int t = threadIdx.x, blk = blockIdx.x;
    for (int i = t; i < NBP; i += 256) hist[i] = 0;
    __syncthreads();
    int e0 = blk * TILE, e1 = min(E, e0 + TILE);
    for (int e = e0 + t; e < e1; e += 256) atomicAdd(&hist[col[e] >> 8], 1);
    __syncthreads();
    for (int b = t; b < NB; b += 256) bcnt[b * ABLK + blk] = hist[b];
}

// A3: LDS-staged reorder, coalesced bucket-grouped write-out of packed records
__global__ __launch_bounds__(256) void bk_scatter_k(const int* __restrict__ row,
                                                    const int* __restrict__ col,
                                                    const float* __restrict__ w,
                                                    const int* __restrict__ sbcnt,
                                                    int2* __restrict__ bpack,
                                                    int E, int NB, int ABLK) {
    __shared__ int2 stage[TILE];
    __shared__ unsigned short stageB[TILE];
    __shared__ int hist[NBP], ofs[NBP], cur[NBP], gbase[NBP];
    __shared__ int wsum[4], wbase[4];
    int t = threadIdx.x, blk = blockIdx.x;
    for (int i = t; i < NBP; i += 256) hist[i] = 0;
    __syncthreads();
    int e0 = blk * TILE, e1 = min(E, e0 + TILE);
    for (int e = e0 + t; e < e1; e += 256) atomicAdd(&hist[col[e] >> 8], 1);
    __syncthreads();
    // exclusive scan over NBP counters (each thread owns 2 slots)
    {
        int c0 = hist[2 * t], c1 = hist[2 * t + 1];
        int s = c0 + c1;
        int lane = t & 63, wid = t >> 6;
        int v = s;
        for (int d = 1; d < 64; d <<= 1) { int u = __shfl_up(v, d); if (lane >= d) v += u; }
        if (lane == 63) wsum[wid] = v;
        __syncthreads();
        if (t == 0) { int r = 0; for (int q = 0; q < 4; ++q) { wbase[q] = r; r += wsum[q]; } }
        __syncthreads();
        int excl = v - s + wbase[wid];
        ofs[2 * t] = excl;          cur[2 * t] = excl;
        ofs[2 * t + 1] = excl + c0; cur[2 * t + 1] = excl + c0;
    }
    __syncthreads();
    for (int b = t; b < NB; b += 256) gbase[b] = sbcnt[b * ABLK + blk] - ofs[b];
    // scatter into LDS by bucket
    for (int e = e0 + t; e < e1; e += 256) {
        int c = col[e];
        int bkt = c >> 8, cl = c & 255;
        int lr = atomicAdd(&cur[bkt], 1);
        stage[lr] = make_int2(row[e] | (cl << 17), __float_as_int(w[e]));
        stageB[lr] = (unsigned short)bkt;
    }
    __syncthreads();
    // coalesced write-out (consecutive slots -> consecutive global dst per bucket run)
    int cntE = e1 - e0;
    for (int s = t; s < cntE; s += 256) {
        int bkt = stageB[s];
        bpack[gbase[bkt] + s] = stage[s];
    }
}

// ================= pass B: per-bucket (256 nodes) ===========================

// B1: per-node in-degree + weighted degree via LDS atomics
__global__ __launch_bounds__(256) void seg_count_k(const int2* __restrict__ bpack,
                                                   const int* __restrict__ sbcnt,
                                                   int* __restrict__ ncnt,
                                                   float* __restrict__ degw,
                                                   int E, int NB, int ABLK) {
    __shared__ int cntL[256];
    __shared__ float degL[256];
    int t = threadIdx.x, b = blockIdx.x;
    cntL[t] = 0; degL[t] = 0.f;
    __syncthreads();
    int p0 = sbcnt[b * ABLK];
    int p1 = (b + 1 < NB) ? sbcnt[(b + 1) * ABLK] : E;
    for (int p = p0 + t; p < p1; p += 256) {
        int2 pk = bpack[p];
        int cl = (pk.x >> 17) & 255;
        atomicAdd(&cntL[cl], 1);
        atomicAdd(&degL[cl], __int_as_float(pk.y));
    }
    __syncthreads();
    int node = b * 256 + t;
    ncnt[node] = cntL[t];
    degw[node] = degL[t];
}

__global__ __launch_bounds__(256) void dinv_k(const float* __restrict__ degw,
                                              float* __restrict__ dinv, int n) {
    int i = blockIdx.x * 256 + threadIdx.x;
    if (i < n) dinv[i] = rsqrtf(1.0f + degw[i]);  // +1 = self-loop weight
}

// B2: place (src, dinv_dst*w*dinv_src) into final CSR order via LDS cursors
__global__ __launch_bounds__(256) void seg_place_k(const int2* __restrict__ bpack,
                                                   const int* __restrict__ sbcnt,
                                                   const int* __restrict__ off,
                                                   const float* __restrict__ dinv,
                                                   int2* __restrict__ fin,
                                                   int E, int n, int NB, int ABLK) {
    __shared__ int curL[256];
    __shared__ float dinvL[256];
    int t = threadIdx.x, b = blockIdx.x;
    int node = b * 256 + t;
    curL[t] = off[node];
    dinvL[t] = (node < n) ? dinv[node] : 0.f;
    __syncthreads();
    int p0 = sbcnt[b * ABLK];
    int p1 = (b + 1 < NB) ? sbcnt[(b + 1) * ABLK] : E;
    for (int p = p0 + t; p < p1; p += 256) {
        int2 pk = bpack[p];
        int src = pk.x & 0x1FFFF;
        int cl = (pk.x >> 17) & 255;
        float wn = dinvL[cl] * __int_as_float(pk.y) * dinv[src];
        int pos = atomicAdd(&curL[cl], 1);
        fin[pos] = make_int2(src, __float_as_int(wn));
    }
}

// ================= h = x @ W1 =================
__global__ __launch_bounds__(256) void gemm1_k(const float* __restrict__ x,
                                               const float* __restrict__ W1,
                                               float* __restrict__ h, int n) {
    __shared__ float w1s[FIN * HID];
    {
        const float4* s4 = (const float4*)W1;
        float4* d4 = (float4*)w1s;
        for (int i = threadIdx.x; i < FIN * HID / 4; i += 256) d4[i] = s4[i];
    }
    __syncthreads();
    int r = blockIdx.x * 256 + threadIdx.x;
    if (r >= n) return;
    const float4* xr = (const float4*)(x + (size_t)r * FIN);
    float acc[HID];
#pragma unroll
    for (int c = 0; c < HID; ++c) acc[c] = 0.f;
    for (int q = 0; q < FIN / 4; ++q) {
        float4 xv = xr[q];
        const float* wk = &w1s[q * 4 * HID];
#pragma unroll
        for (int c = 0; c < HID; ++c)
            acc[c] += xv.x * wk[c] + xv.y * wk[HID + c] +
                      xv.z * wk[2 * HID + c] + xv.w * wk[3 * HID + c];
    }
    float4* hv = (float4*)(h + (size_t)r * HID);
#pragma unroll
    for (int q = 0; q < HID / 4; ++q)
        hv[q] = make_float4(acc[4 * q], acc[4 * q + 1], acc[4 * q + 2], acc[4 * q + 3]);
}

// ================= gather aggregation (no atomics) =================
template <int RELU>
__global__ __launch_bounds__(256) void agg_gather_k(const float* __restrict__ hin,
                                                    const float* __restrict__ dinv,
                                                    const int* __restrict__ off,
                                                    const int* __restrict__ cnt,
                                                    const int2* __restrict__ pair,
                                                    const float* __restrict__ b1,
                                                    float* __restrict__ out, int n) {
    int tid = blockIdx.x * 256 + threadIdx.x;
    int i = tid >> 4;
    if (i >= n) return;
    int lane = tid & 15;
    float di = dinv[i];
    float acc0 = di * di * hin[(size_t)i * HID + lane];
    float acc1 = 0.f, acc2 = 0.f, acc3 = 0.f;
    int p = off[i], e = p + cnt[i];
    for (; p + 3 < e; p += 4) {
        int2 a = pair[p], b = pair[p + 1], c = pair[p + 2], d = pair[p + 3];
        acc0 += __int_as_float(a.y) * hin[(size_t)a.x * HID + lane];
        acc1 += __int_as_float(b.y) * hin[(size_t)b.x * HID + lane];
        acc2 += __int_as_float(c.y) * hin[(size_t)c.x * HID + lane];
        acc3 += __int_as_float(d.y) * hin[(size_t)d.x * HID + lane];
    }
    for (; p < e; ++p) {
        int2 a = pair[p];
        acc0 += __int_as_float(a.y) * hin[(size_t)a.x * HID + lane];
    }
    float v = (acc0 + acc1) + (acc2 + acc3);
    if (RELU) v = fmaxf(v + b1[lane], 0.f);
    out[(size_t)i * HID + lane] = v;
}

// out = log_softmax(agg2 @ W2 + b2)
__global__ __launch_bounds__(256) void out_k(const float* __restrict__ agg2,
                                             const float* __restrict__ W2,
                                             const float* __restrict__ b2,
                                             float* __restrict__ out, int n) {
    __shared__ float w2s[HID * CLS];
    __shared__ float b2s[CLS];
    for (int i = threadIdx.x; i < HID * CLS; i += 256) w2s[i] = W2[i];
    if (threadIdx.x < CLS) b2s[threadIdx.x] = b2[threadIdx.x];
    __syncthreads();
    int i = blockIdx.x * 256 + threadIdx.x;
    if (i >= n) return;
    float a[HID];
    const float4* av = (const float4*)(agg2 + (size_t)i * HID);
#pragma unroll
    for (int q = 0; q < HID / 4; ++q) {
        float4 v = av[q];
        a[4 * q] = v.x; a[4 * q + 1] = v.y; a[4 * q + 2] = v.z; a[4 * q + 3] = v.w;
    }
    float z[CLS];
#pragma unroll
    for (int c = 0; c < CLS; ++c) z[c] = b2s[c];
#pragma unroll
    for (int k = 0; k < HID; ++k) {
        float ak = a[k];
#pragma unroll
        for (int c = 0; c < CLS; ++c) z[c] += ak * w2s[k * CLS + c];
    }
    float m = z[0];
#pragma unroll
    for (int c = 1; c < CLS; ++c) m = fmaxf(m, z[c]);
    float s = 0.f;
#pragma unroll
    for (int c = 0; c < CLS; ++c) s += __expf(z[c] - m);
    float l = __logf(s);
    float* o = out + (size_t)i * CLS;
#pragma unroll
    for (int c = 0; c < CLS; ++c) o[c] = z[c] - m - l;
}

extern "C" void kernel_launch(void* const* d_in, const int* in_sizes, int n_in,
                              void* d_out, int out_size, void* d_ws, size_t ws_size,
                              hipStream_t stream) {
    const float* x  = (const float*)d_in[0];
    const float* ew = (const float*)d_in[1];
    const float* W1 = (const float*)d_in[2];
    const float* b1 = (const float*)d_in[3];
    const float* W2 = (const float*)d_in[4];
    const float* b2 = (const float*)d_in[5];
    const int*   ei = (const int*)d_in[6];

    int n = in_sizes[0] / FIN;   // 100000
    int E = in_sizes[1];         // 3200000
    const int* row = ei;
    const int* col = ei + E;

    int NB   = (n + 255) >> 8;            // 391 buckets of 256 nodes
    int NN   = NB * 256;                  // padded node count (100096)
    int ABLK = (E + TILE - 1) / TILE;     // 800 bucketize blocks
    int M1   = NB * ABLK;                 // per-(bucket,block) count matrix

    // workspace layout (4B units)
    int*   bcnt  = (int*)d_ws;                 // M1
    int*   sbcnt = bcnt + M1;                  // M1
    int*   bsum  = sbcnt + M1;                 // 1024
    int*   ncnt  = bsum + 1024;                // NN
    int*   off   = ncnt + NN;                  // NN
    float* degw  = (float*)(off + NN);         // NN
    float* dinv  = degw + NN;                  // NN
    int*   base2 = (int*)(dinv + NN);
    int2*  bpack = (int2*)base2;               // E int2  (reused below)
    int2*  fin   = bpack + E;                  // E int2
    // bpack region is dead after seg_place_k; reuse for dense activations:
    float* h    = (float*)base2;               // 16n
    float* h1   = h + (size_t)16 * n;          // 16n
    float* agg2 = h1 + (size_t)16 * n;         // 16n  (48n <= 2E)
    float* outp = (float*)d_out;

    dim3 b(256);
    int G1 = (M1 + 1023) / 1024;
    int G2 = (NN + 1023) / 1024;

    // pass A: bucketize
    bk_count_k<<<ABLK, b, 0, stream>>>(col, bcnt, E, NB, ABLK);
    scan1_k<<<G1, b, 0, stream>>>(bcnt, bsum, M1);
    scan2_k<<<1, 64, 0, stream>>>(bsum, G1);
    scan3_k<<<G1, b, 0, stream>>>(bcnt, bsum, sbcnt, M1);
    bk_scatter_k<<<ABLK, b, 0, stream>>>(row, col, ew, sbcnt, bpack, E, NB, ABLK);

    // pass B: per-bucket degree, dinv, CSR offsets, final placement with norm
    seg_count_k<<<NB, b, 0, stream>>>(bpack, sbcnt, ncnt, degw, E, NB, ABLK);
    dinv_k<<<(n + 255) / 256, b, 0, stream>>>(degw, dinv, n);
    scan1_k<<<G2, b, 0, stream>>>(ncnt, bsum, NN);
    scan2_k<<<1, 64, 0, stream>>>(bsum, G2);
    scan3_k<<<G2, b, 0, stream>>>(ncnt, bsum, off, NN);
    seg_place_k<<<NB, b, 0, stream>>>(bpack, sbcnt, off, dinv, fin, E, n, NB, ABLK);

    // dense pipeline (h aliases dead bpack region)
    gemm1_k<<<(n + 255) / 256, b, 0, stream>>>(x, W1, h, n);
    int gnodes16 = (n * HID + 255) / 256;
    agg_gather_k<1><<<gnodes16, b, 0, stream>>>(h, dinv, off, ncnt, fin, b1, h1, n);
    agg_gather_k<0><<<gnodes16, b, 0, stream>>>(h1, dinv, off, ncnt, fin, b1, agg2, n);

    out_k<<<(n + 255) / 256, b, 0, stream>>>(agg2, W2, b2, outp, n);
}

// Round 5
// 281.687 us; speedup vs baseline: 5.5692x; 1.3039x over previous
//
#include <hip/hip_runtime.h>
#include <hip/hip_bf16.h>

#define HID 16
#define CLS 40
#define FIN 512
#define TILE 4000     // edges per bucketize block
#define NBP 512       // padded bucket count; requires n <= 131072 (src fits 17 bits)

typedef unsigned int uint;
typedef unsigned short ushort;

__device__ __forceinline__ ushort f2bf(float f) {
    uint u = __float_as_uint(f);
    u += 0x7FFF + ((u >> 16) & 1);   // round-to-nearest-even
    return (ushort)(u >> 16);
}
__device__ __forceinline__ float bf2f(ushort h) {
    return __uint_as_float((uint)h << 16);
}

// ================= hierarchical exclusive scan =================

__global__ __launch_bounds__(256) void scan1_k(const int* __restrict__ cnt,
                                               int* __restrict__ bsum, int M) {
    __shared__ int ws[4];
    int b = blockIdx.x, t = threadIdx.x;
    int i0 = b * 1024 + t * 4;
    int s = 0;
#pragma unroll
    for (int q = 0; q < 4; ++q) if (i0 + q < M) s += cnt[i0 + q];
    for (int d = 32; d > 0; d >>= 1) s += __shfl_xor(s, d);
    int lane = t & 63, wid = t >> 6;
    if (lane == 0) ws[wid] = s;
    __syncthreads();
    if (t == 0) bsum[b] = ws[0] + ws[1] + ws[2] + ws[3];
}

// parallel in-place exclusive scan of bsum[0..G), G <= 1024, single block
__global__ __launch_bounds__(256) void scan2p_k(int* __restrict__ bsum, int G) {
    __shared__ int wsum[4], wbase[4];
    int t = threadIdx.x;
    int i0 = t * 4;
    int c[4];
#pragma unroll
    for (int q = 0; q < 4; ++q) c[q] = (i0 + q < G) ? bsum[i0 + q] : 0;
    int s = c[0] + c[1] + c[2] + c[3];
    int lane = t & 63, wid = t >> 6;
    int v = s;
    for (int d = 1; d < 64; d <<= 1) { int u = __shfl_up(v, d); if (lane >= d) v += u; }
    if (lane == 63) wsum[wid] = v;
    __syncthreads();
    if (t == 0) { int r = 0; for (int q = 0; q < 4; ++q) { wbase[q] = r; r += wsum[q]; } }
    __syncthreads();
    int o = v - s + wbase[wid];
#pragma unroll
    for (int q = 0; q < 4; ++q) {
        if (i0 + q < G) { bsum[i0 + q] = o; o += c[q]; }
    }
}

__global__ __launch_bounds__(256) void scan3_k(const int* __restrict__ cnt,
                                               const int* __restrict__ bsum,
                                               int* __restrict__ sout, int M) {
    __shared__ int wsum[4];
    __shared__ int wbase[4];
    int b = blockIdx.x, t = threadIdx.x;
    int i0 = b * 1024 + t * 4;
    int c[4];
#pragma unroll
    for (int q = 0; q < 4; ++q) c[q] = (i0 + q < M) ? cnt[i0 + q] : 0;
    int s = c[0] + c[1] + c[2] + c[3];
    int lane = t & 63, wid = t >> 6;
    int v = s;
    for (int d = 1; d < 64; d <<= 1) { int u = __shfl_up(v, d); if (lane >= d) v += u; }
    if (lane == 63) wsum[wid] = v;
    __syncthreads();
    if (t == 0) { int r = 0; for (int q = 0; q < 4; ++q) { wbase[q] = r; r += wsum[q]; } }
    __syncthreads();
    int o = v - s + wbase[wid] + bsum[b];
#pragma unroll
    for (int q = 0; q < 4; ++q) {
        if (i0 + q < M) { sout[i0 + q] = o; o += c[q]; }
    }
}

// ================= pass A: bucketize by col>>8 (LDS atomics only) ===========

__global__ __launch_bounds__(256) void bk_count_k(const int* __restrict__ col,
                                                  int* __restrict__ bcnt,
                                                  int E, int NB, int ABLK) {
    __shared__ int hist[NBP];
    int t = threadIdx.x, blk = blockIdx.x;
    for (int i = t; i < NBP; i += 256) hist[i] = 0;
    __syncthreads();
    int e0 = blk * TILE, e1 = min(E, e0 + TILE);
    for (int e = e0 + t; e < e1; e += 256) atomicAdd(&hist[col[e] >> 8], 1);
    __syncthreads();
    for (int b = t; b < NB; b += 256) bcnt[b * ABLK + blk] = hist[b];
}

__global__ __launch_bounds__(256) void bk_scatter_k(const int* __restrict__ row,
                                                    const int* __restrict__ col,
                                                    const float* __restrict__ w,
                                                    const int* __restrict__ sbcnt,
                                                    int2* __restrict__ bpack,
                                                    int E, int NB, int ABLK) {
    __shared__ int2 stage[TILE];
    __shared__ ushort stageB[TILE];
    __shared__ int hist[NBP], ofs[NBP], cur[NBP], gbase[NBP];
    __shared__ int wsum[4], wbase[4];
    int t = threadIdx.x, blk = blockIdx.x;
    for (int i = t; i < NBP; i += 256) hist[i] = 0;
    __syncthreads();
    int e0 = blk * TILE, e1 = min(E, e0 + TILE);
    for (int e = e0 + t; e < e1; e += 256) atomicAdd(&hist[col[e] >> 8], 1);
    __syncthreads();
    {
        int c0 = hist[2 * t], c1 = hist[2 * t + 1];
        int s = c0 + c1;
        int lane = t & 63, wid = t >> 6;
        int v = s;
        for (int d = 1; d < 64; d <<= 1) { int u = __shfl_up(v, d); if (lane >= d) v += u; }
        if (lane == 63) wsum[wid] = v;
        __syncthreads();
        if (t == 0) { int r = 0; for (int q = 0; q < 4; ++q) { wbase[q] = r; r += wsum[q]; } }
        __syncthreads();
        int excl = v - s + wbase[wid];
        ofs[2 * t] = excl;          cur[2 * t] = excl;
        ofs[2 * t + 1] = excl + c0; cur[2 * t + 1] = excl + c0;
    }
    __syncthreads();
    for (int b = t; b < NB; b += 256) gbase[b] = sbcnt[b * ABLK + blk] - ofs[b];
    for (int e = e0 + t; e < e1; e += 256) {
        int c = col[e];
        int bkt = c >> 8, cl = c & 255;
        int lr = atomicAdd(&cur[bkt], 1);
        stage[lr] = make_int2(row[e] | (cl << 17), __float_as_int(w[e]));
        stageB[lr] = (ushort)bkt;
    }
    __syncthreads();
    int cntE = e1 - e0;
    for (int s = t; s < cntE; s += 256) {
        int bkt = stageB[s];
        bpack[gbase[bkt] + s] = stage[s];
    }
}

// ================= pass B: per-bucket (256 nodes) ===========================

// B1: per-node in-degree + weighted degree via LDS atomics; dinv fused
__global__ __launch_bounds__(256) void seg_count_k(const int2* __restrict__ bpack,
                                                   const int* __restrict__ sbcnt,
                                                   int* __restrict__ ncnt,
                                                   float* __restrict__ dinv,
                                                   int E, int NB, int ABLK) {
    __shared__ int cntL[256];
    __shared__ float degL[256];
    int t = threadIdx.x, b = blockIdx.x;
    cntL[t] = 0; degL[t] = 0.f;
    __syncthreads();
    int p0 = sbcnt[b * ABLK];
    int p1 = (b + 1 < NB) ? sbcnt[(b + 1) * ABLK] : E;
    for (int p = p0 + t; p < p1; p += 256) {
        int2 pk = bpack[p];
        int cl = (pk.x >> 17) & 255;
        atomicAdd(&cntL[cl], 1);
        atomicAdd(&degL[cl], __int_as_float(pk.y));
    }
    __syncthreads();
    int node = b * 256 + t;
    ncnt[node] = cntL[t];
    dinv[node] = rsqrtf(1.0f + degL[t]);   // +1 = self-loop weight
}

// B2: place packed (src | bf15(wn)<<17) into CSR order via LDS cursors
__global__ __launch_bounds__(256) void seg_place_k(const int2* __restrict__ bpack,
                                                   const int* __restrict__ sbcnt,
                                                   const int* __restrict__ off,
                                                   const float* __restrict__ dinv,
                                                   uint* __restrict__ fin,
                                                   int E, int n, int NB, int ABLK) {
    __shared__ int curL[256];
    __shared__ float dinvL[256];
    int t = threadIdx.x, b = blockIdx.x;
    int node = b * 256 + t;
    curL[t] = off[node];
    dinvL[t] = (node < n) ? dinv[node] : 0.f;
    __syncthreads();
    int p0 = sbcnt[b * ABLK];
    int p1 = (b + 1 < NB) ? sbcnt[(b + 1) * ABLK] : E;
    for (int p = p0 + t; p < p1; p += 256) {
        int2 pk = bpack[p];
        uint src = (uint)pk.x & 0x1FFFFu;
        int cl = (pk.x >> 17) & 255;
        float wn = dinvL[cl] * __int_as_float(pk.y) * dinv[src];
        uint wb = __float_as_uint(wn) + 0x8000u;   // round mantissa (wn >= 0)
        int pos = atomicAdd(&curL[cl], 1);
        fin[pos] = src | ((wb >> 16) << 17);
    }
}

// ================= h = x @ W1 (bf16 output) =================
__global__ __launch_bounds__(256) void gemm1_k(const float* __restrict__ x,
                                               const float* __restrict__ W1,
                                               ushort* __restrict__ h, int n) {
    __shared__ float w1s[FIN * HID];
    {
        const float4* s4 = (const float4*)W1;
        float4* d4 = (float4*)w1s;
        for (int i = threadIdx.x; i < FIN * HID / 4; i += 256) d4[i] = s4[i];
    }
    __syncthreads();
    int r = blockIdx.x * 256 + threadIdx.x;
    if (r >= n) return;
    const float4* xr = (const float4*)(x + (size_t)r * FIN);
    float acc[HID];
#pragma unroll
    for (int c = 0; c < HID; ++c) acc[c] = 0.f;
    for (int q = 0; q < FIN / 4; ++q) {
        float4 xv = xr[q];
        const float* wk = &w1s[q * 4 * HID];
#pragma unroll
        for (int c = 0; c < HID; ++c)
            acc[c] += xv.x * wk[c] + xv.y * wk[HID + c] +
                      xv.z * wk[2 * HID + c] + xv.w * wk[3 * HID + c];
    }
    uint pk[HID / 2];
#pragma unroll
    for (int q = 0; q < HID / 2; ++q)
        pk[q] = (uint)f2bf(acc[2 * q]) | ((uint)f2bf(acc[2 * q + 1]) << 16);
    uint4* hv = (uint4*)(h + (size_t)r * HID);
    hv[0] = make_uint4(pk[0], pk[1], pk[2], pk[3]);
    hv[1] = make_uint4(pk[4], pk[5], pk[6], pk[7]);
}

// ================= gather aggregation (no atomics, bf16 table) ==============
// layer 1: out bf16 = relu(agg + b1);  layer 2: out f32 = agg
__global__ __launch_bounds__(256) void agg1_k(const ushort* __restrict__ hin,
                                              const float* __restrict__ dinv,
                                              const int* __restrict__ off,
                                              const int* __restrict__ cnt,
                                              const uint* __restrict__ fin,
                                              const float* __restrict__ b1,
                                              ushort* __restrict__ out, int n) {
    int tid = blockIdx.x * 256 + threadIdx.x;
    int i = tid >> 4;
    if (i >= n) return;
    int lane = tid & 15;
    float di = dinv[i];
    float acc0 = di * di * bf2f(hin[(size_t)i * HID + lane]);
    float acc1 = 0.f, acc2 = 0.f, acc3 = 0.f;
    int p = off[i], e = p + cnt[i];
    for (; p + 3 < e; p += 4) {
        uint a = fin[p], b = fin[p + 1], c = fin[p + 2], d = fin[p + 3];
        acc0 += __uint_as_float((a >> 17) << 16) * bf2f(hin[(size_t)(a & 0x1FFFFu) * HID + lane]);
        acc1 += __uint_as_float((b >> 17) << 16) * bf2f(hin[(size_t)(b & 0x1FFFFu) * HID + lane]);
        acc2 += __uint_as_float((c >> 17) << 16) * bf2f(hin[(size_t)(c & 0x1FFFFu) * HID + lane]);
        acc3 += __uint_as_float((d >> 17) << 16) * bf2f(hin[(size_t)(d & 0x1FFFFu) * HID + lane]);
    }
    for (; p < e; ++p) {
        uint a = fin[p];
        acc0 += __uint_as_float((a >> 17) << 16) * bf2f(hin[(size_t)(a & 0x1FFFFu) * HID + lane]);
    }
    float v = (acc0 + acc1) + (acc2 + acc3);
    v = fmaxf(v + b1[lane], 0.f);
    out[(size_t)i * HID + lane] = f2bf(v);
}

__global__ __launch_bounds__(256) void agg2_k(const ushort* __restrict__ hin,
                                              const float* __restrict__ dinv,
                                              const int* __restrict__ off,
                                              const int* __restrict__ cnt,
                                              const uint* __restrict__ fin,
                                              float* __restrict__ out, int n) {
    int tid = blockIdx.x * 256 + threadIdx.x;
    int i = tid >> 4;
    if (i >= n) return;
    int lane = tid & 15;
    float di = dinv[i];
    float acc0 = di * di * bf2f(hin[(size_t)i * HID + lane]);
    float acc1 = 0.f, acc2 = 0.f, acc3 = 0.f;
    int p = off[i], e = p + cnt[i];
    for (; p + 3 < e; p += 4) {
        uint a = fin[p], b = fin[p + 1], c = fin[p + 2], d = fin[p + 3];
        acc0 += __uint_as_float((a >> 17) << 16) * bf2f(hin[(size_t)(a & 0x1FFFFu) * HID + lane]);
        acc1 += __uint_as_float((b >> 17) << 16) * bf2f(hin[(size_t)(b & 0x1FFFFu) * HID + lane]);
        acc2 += __uint_as_float((c >> 17) << 16) * bf2f(hin[(size_t)(c & 0x1FFFFu) * HID + lane]);
        acc3 += __uint_as_float((d >> 17) << 16) * bf2f(hin[(size_t)(d & 0x1FFFFu) * HID + lane]);
    }
    for (; p < e; ++p) {
        uint a = fin[p];
        acc0 += __uint_as_float((a >> 17) << 16) * bf2f(hin[(size_t)(a & 0x1FFFFu) * HID + lane]);
    }
    out[(size_t)i * HID + lane] = (acc0 + acc1) + (acc2 + acc3);
}

// out = log_softmax(agg2 @ W2 + b2)
__global__ __launch_bounds__(256) void out_k(const float* __restrict__ agg2,
                                             const float* __restrict__ W2,
                                             const float* __restrict__ b2,
                                             float* __restrict__ out, int n) {
    __shared__ float w2s[HID * CLS];
    __shared__ float b2s[CLS];
    for (int i = threadIdx.x; i < HID * CLS; i += 256) w2s[i] = W2[i];
    if (threadIdx.x < CLS) b2s[threadIdx.x] = b2[threadIdx.x];
    __syncthreads();
    int i = blockIdx.x * 256 + threadIdx.x;
    if (i >= n) return;
    float a[HID];
    const float4* av = (const float4*)(agg2 + (size_t)i * HID);
#pragma unroll
    for (int q = 0; q < HID / 4; ++q) {
        float4 v = av[q];
        a[4 * q] = v.x; a[4 * q + 1] = v.y; a[4 * q + 2] = v.z; a[4 * q + 3] = v.w;
    }
    float z[CLS];
#pragma unroll
    for (int c = 0; c < CLS; ++c) z[c] = b2s[c];
#pragma unroll
    for (int k = 0; k < HID; ++k) {
        float ak = a[k];
#pragma unroll
        for (int c = 0; c < CLS; ++c) z[c] += ak * w2s[k * CLS + c];
    }
    float m = z[0];
#pragma unroll
    for (int c = 1; c < CLS; ++c) m = fmaxf(m, z[c]);
    float s = 0.f;
#pragma unroll
    for (int c = 0; c < CLS; ++c) s += __expf(z[c] - m);
    float l = __logf(s);
    float* o = out + (size_t)i * CLS;
#pragma unroll
    for (int c = 0; c < CLS; ++c) o[c] = z[c] - m - l;
}

extern "C" void kernel_launch(void* const* d_in, const int* in_sizes, int n_in,
                              void* d_out, int out_size, void* d_ws, size_t ws_size,
                              hipStream_t stream) {
    const float* x  = (const float*)d_in[0];
    const float* ew = (const float*)d_in[1];
    const float* W1 = (const float*)d_in[2];
    const float* b1 = (const float*)d_in[3];
    const float* W2 = (const float*)d_in[4];
    const float* b2 = (const float*)d_in[5];
    const int*   ei = (const int*)d_in[6];

    int n = in_sizes[0] / FIN;   // 100000
    int E = in_sizes[1];         // 3200000
    const int* row = ei;
    const int* col = ei + E;

    int NB   = (n + 255) >> 8;            // 391 buckets of 256 nodes
    int NN   = NB * 256;                  // padded node count
    int ABLK = (E + TILE - 1) / TILE;     // 800 bucketize blocks
    int M1   = NB * ABLK;

    // workspace layout (4B units)
    int*   bcnt  = (int*)d_ws;                 // M1
    int*   sbcnt = bcnt + M1;                  // M1
    int*   bsum  = sbcnt + M1;                 // 1024
    int*   ncnt  = bsum + 1024;                // NN
    int*   off   = ncnt + NN;                  // NN
    float* dinv  = (float*)(off + NN);         // NN
    uint*  fin   = (uint*)(dinv + NN);         // E
    int*   base2 = (int*)(fin + E);
    int2*  bpack = (int2*)base2;               // E int2 (dead after seg_place)
    // aliases into dead bpack region:
    ushort* h    = (ushort*)base2;             // 16n bf16
    ushort* h1   = h + (size_t)16 * n;         // 16n bf16
    float*  agg2 = (float*)(h1 + (size_t)16 * n); // 16n f32   (total 16n*4B+... < 2E*8B)
    float*  outp = (float*)d_out;

    dim3 b(256);
    int G1 = (M1 + 1023) / 1024;
    int G2 = (NN + 1023) / 1024;

    // pass A: bucketize
    bk_count_k<<<ABLK, b, 0, stream>>>(col, bcnt, E, NB, ABLK);
    scan1_k<<<G1, b, 0, stream>>>(bcnt, bsum, M1);
    scan2p_k<<<1, b, 0, stream>>>(bsum, G1);
    scan3_k<<<G1, b, 0, stream>>>(bcnt, bsum, sbcnt, M1);
    bk_scatter_k<<<ABLK, b, 0, stream>>>(row, col, ew, sbcnt, bpack, E, NB, ABLK);

    // pass B: degrees + dinv, CSR offsets, normalized packed placement
    seg_count_k<<<NB, b, 0, stream>>>(bpack, sbcnt, ncnt, dinv, E, NB, ABLK);
    scan1_k<<<G2, b, 0, stream>>>(ncnt, bsum, NN);
    scan2p_k<<<1, b, 0, stream>>>(bsum, G2);
    scan3_k<<<G2, b, 0, stream>>>(ncnt, bsum, off, NN);
    seg_place_k<<<NB, b, 0, stream>>>(bpack, sbcnt, off, dinv, fin, E, n, NB, ABLK);

    // dense pipeline (h aliases dead bpack region)
    gemm1_k<<<(n + 255) / 256, b, 0, stream>>>(x, W1, h, n);
    int gnodes16 = (n * HID + 255) / 256;
    agg1_k<<<gnodes16, b, 0, stream>>>(h, dinv, off, ncnt, fin, b1, h1, n);
    agg2_k<<<gnodes16, b, 0, stream>>>(h1, dinv, off, ncnt, fin, agg2, n);

    out_k<<<(n + 255) / 256, b, 0, stream>>>(agg2, W2, b2, outp, n);
}

// Round 6
// 269.472 us; speedup vs baseline: 5.8217x; 1.0453x over previous
//
#include <hip/hip_runtime.h>
#include <hip/hip_bf16.h>

#define HID 16
#define CLS 40
#define FIN 512
#define TILE 4000     // edges per bucketize block
#define NBP 1024      // padded bucket count (buckets of 128 nodes; n <= 131072)

typedef unsigned int uint;
typedef unsigned short ushort;

__device__ __forceinline__ ushort f2bf(float f) {
    uint u = __float_as_uint(f);
    u += 0x7FFF + ((u >> 16) & 1);   // round-to-nearest-even
    return (ushort)(u >> 16);
}
__device__ __forceinline__ float bf2f(ushort h) {
    return __uint_as_float((uint)h << 16);
}
// decode bf15 weight packed in bits [31:17]
__device__ __forceinline__ float wdec(uint a) {
    return __uint_as_float((a >> 17) << 16);
}

// ================= hierarchical exclusive scan (M1 elements) =================

__global__ __launch_bounds__(256) void scan1_k(const int* __restrict__ cnt,
                                               int* __restrict__ bsum, int M) {
    __shared__ int ws[4];
    int b = blockIdx.x, t = threadIdx.x;
    int i0 = b * 1024 + t * 4;
    int s = 0;
#pragma unroll
    for (int q = 0; q < 4; ++q) if (i0 + q < M) s += cnt[i0 + q];
    for (int d = 32; d > 0; d >>= 1) s += __shfl_xor(s, d);
    int lane = t & 63, wid = t >> 6;
    if (lane == 0) ws[wid] = s;
    __syncthreads();
    if (t == 0) bsum[b] = ws[0] + ws[1] + ws[2] + ws[3];
}

// parallel in-place exclusive scan of bsum[0..G), G <= 1024, single block
__global__ __launch_bounds__(256) void scan2p_k(int* __restrict__ bsum, int G) {
    __shared__ int wsum[4], wbase[4];
    int t = threadIdx.x;
    int i0 = t * 4;
    int c[4];
#pragma unroll
    for (int q = 0; q < 4; ++q) c[q] = (i0 + q < G) ? bsum[i0 + q] : 0;
    int s = c[0] + c[1] + c[2] + c[3];
    int lane = t & 63, wid = t >> 6;
    int v = s;
    for (int d = 1; d < 64; d <<= 1) { int u = __shfl_up(v, d); if (lane >= d) v += u; }
    if (lane == 63) wsum[wid] = v;
    __syncthreads();
    if (t == 0) { int r = 0; for (int q = 0; q < 4; ++q) { wbase[q] = r; r += wsum[q]; } }
    __syncthreads();
    int o = v - s + wbase[wid];
#pragma unroll
    for (int q = 0; q < 4; ++q) {
        if (i0 + q < G) { bsum[i0 + q] = o; o += c[q]; }
    }
}

__global__ __launch_bounds__(256) void scan3_k(const int* __restrict__ cnt,
                                               const int* __restrict__ bsum,
                                               int* __restrict__ sout, int M) {
    __shared__ int wsum[4];
    __shared__ int wbase[4];
    int b = blockIdx.x, t = threadIdx.x;
    int i0 = b * 1024 + t * 4;
    int c[4];
#pragma unroll
    for (int q = 0; q < 4; ++q) c[q] = (i0 + q < M) ? cnt[i0 + q] : 0;
    int s = c[0] + c[1] + c[2] + c[3];
    int lane = t & 63, wid = t >> 6;
    int v = s;
    for (int d = 1; d < 64; d <<= 1) { int u = __shfl_up(v, d); if (lane >= d) v += u; }
    if (lane == 63) wsum[wid] = v;
    __syncthreads();
    if (t == 0) { int r = 0; for (int q = 0; q < 4; ++q) { wbase[q] = r; r += wsum[q]; } }
    __syncthreads();
    int o = v - s + wbase[wid] + bsum[b];
#pragma unroll
    for (int q = 0; q < 4; ++q) {
        if (i0 + q < M) { sout[i0 + q] = o; o += c[q]; }
    }
}

// ================= pass A: bucketize by col>>7 (LDS atomics only) ===========

__global__ __launch_bounds__(256) void bk_count_k(const int* __restrict__ col,
                                                  int* __restrict__ bcnt,
                                                  int E, int NB, int ABLK) {
    __shared__ int hist[NBP];
    int t = threadIdx.x, blk = blockIdx.x;
    for (int i = t; i < NBP; i += 256) hist[i] = 0;
    __syncthreads();
    int e0 = blk * TILE, e1 = min(E, e0 + TILE);
    for (int e = e0 + t; e < e1; e += 256) atomicAdd(&hist[col[e] >> 7], 1);
    __syncthreads();
    for (int b = t; b < NB; b += 256) bcnt[b * ABLK + blk] = hist[b];
}

__global__ __launch_bounds__(256) void bk_scatter_k(const int* __restrict__ row,
                                                    const int* __restrict__ col,
                                                    const float* __restrict__ w,
                                                    const int* __restrict__ sbcnt,
                                                    int2* __restrict__ bpack,
                                                    int E, int NB, int ABLK) {
    __shared__ int2 stage[TILE];
    __shared__ ushort stageB[TILE];
    __shared__ int hist[NBP], ofs[NBP], cur[NBP], gbase[NBP];
    __shared__ int wsum[4], wbase[4];
    int t = threadIdx.x, blk = blockIdx.x;
    for (int i = t; i < NBP; i += 256) hist[i] = 0;
    __syncthreads();
    int e0 = blk * TILE, e1 = min(E, e0 + TILE);
    for (int e = e0 + t; e < e1; e += 256) atomicAdd(&hist[col[e] >> 7], 1);
    __syncthreads();
    {
        // exclusive scan over NBP=1024 counters; each thread owns 4 slots
        int c0 = hist[4 * t], c1 = hist[4 * t + 1], c2 = hist[4 * t + 2], c3 = hist[4 * t + 3];
        int s = c0 + c1 + c2 + c3;
        int lane = t & 63, wid = t >> 6;
        int v = s;
        for (int d = 1; d < 64; d <<= 1) { int u = __shfl_up(v, d); if (lane >= d) v += u; }
        if (lane == 63) wsum[wid] = v;
        __syncthreads();
        if (t == 0) { int r = 0; for (int q = 0; q < 4; ++q) { wbase[q] = r; r += wsum[q]; } }
        __syncthreads();
        int o = v - s + wbase[wid];
        ofs[4 * t] = o;     cur[4 * t] = o;     o += c0;
        ofs[4 * t + 1] = o; cur[4 * t + 1] = o; o += c1;
        ofs[4 * t + 2] = o; cur[4 * t + 2] = o; o += c2;
        ofs[4 * t + 3] = o; cur[4 * t + 3] = o;
    }
    __syncthreads();
    for (int b = t; b < NB; b += 256) gbase[b] = sbcnt[b * ABLK + blk] - ofs[b];
    for (int e = e0 + t; e < e1; e += 256) {
        int c = col[e];
        int bkt = c >> 7, cl = c & 127;
        int lr = atomicAdd(&cur[bkt], 1);
        stage[lr] = make_int2(row[e] | (cl << 17), __float_as_int(w[e]));
        stageB[lr] = (ushort)bkt;
    }
    __syncthreads();
    int cntE = e1 - e0;
    for (int s = t; s < cntE; s += 256) {
        int bkt = stageB[s];
        bpack[gbase[bkt] + s] = stage[s];
    }
}

// ====== pass B (fused): per-bucket count + local scan + dinv + place ========
// CSR base for bucket b is sbcnt[b*ABLK] (edges already bucket-contiguous),
// so offsets are purely local -> no global scan, no second kernel.
__global__ __launch_bounds__(256) void seg_build_k(const int2* __restrict__ bpack,
                                                   const int* __restrict__ sbcnt,
                                                   int* __restrict__ off,
                                                   float* __restrict__ dinv,
                                                   uint* __restrict__ fin,
                                                   int E, int NB, int ABLK, int NN) {
    __shared__ int cntL[128];
    __shared__ float degL[128];
    __shared__ int curL[128];
    __shared__ int wtot[4];
    int t = threadIdx.x, b = blockIdx.x;
    if (t < 128) { cntL[t] = 0; degL[t] = 0.f; }
    __syncthreads();
    int p0 = sbcnt[b * ABLK];
    int p1 = (b + 1 < NB) ? sbcnt[(b + 1) * ABLK] : E;
    for (int p = p0 + t; p < p1; p += 256) {
        int2 pk = bpack[p];
        int cl = (pk.x >> 17) & 127;
        atomicAdd(&cntL[cl], 1);
        atomicAdd(&degL[cl], __int_as_float(pk.y));
    }
    __syncthreads();
    // exclusive scan of cntL[0..127] (upper 128 threads carry zeros)
    int c = (t < 128) ? cntL[t] : 0;
    int lane = t & 63, wid = t >> 6;
    int v = c;
    for (int d = 1; d < 64; d <<= 1) { int u = __shfl_up(v, d); if (lane >= d) v += u; }
    if (lane == 63) wtot[wid] = v;
    __syncthreads();
    if (t < 128) {
        int excl = p0 + ((wid == 1) ? wtot[0] : 0) + v - c;
        int node = b * 128 + t;
        off[node] = excl;
        curL[t] = excl;
        dinv[node] = rsqrtf(1.0f + degL[t]);   // +1 = self-loop weight
    }
    if (b == NB - 1 && t == 0) off[NN] = E;
    __syncthreads();
    for (int p = p0 + t; p < p1; p += 256) {
        int2 pk = bpack[p];
        uint src = (uint)pk.x & 0x1FFFFu;
        int cl = (pk.x >> 17) & 127;
        uint u = __float_as_uint(__int_as_float(pk.y)) + 0x8000u;  // raw w, bf15 round
        int pos = atomicAdd(&curL[cl], 1);
        fin[pos] = src | ((u >> 16) << 17);
    }
}

// ================= g = dinv .* (x @ W1)   (bf16 output) =====================
__global__ __launch_bounds__(256) void gemm1_k(const float* __restrict__ x,
                                               const float* __restrict__ W1,
                                               const float* __restrict__ dinv,
                                               ushort* __restrict__ g, int n) {
    __shared__ float w1s[FIN * HID];
    {
        const float4* s4 = (const float4*)W1;
        float4* d4 = (float4*)w1s;
        for (int i = threadIdx.x; i < FIN * HID / 4; i += 256) d4[i] = s4[i];
    }
    __syncthreads();
    int r = blockIdx.x * 256 + threadIdx.x;
    if (r >= n) return;
    const float4* xr = (const float4*)(x + (size_t)r * FIN);
    float acc[HID];
#pragma unroll
    for (int c = 0; c < HID; ++c) acc[c] = 0.f;
    for (int q = 0; q < FIN / 4; ++q) {
        float4 xv = xr[q];
        const float* wk = &w1s[q * 4 * HID];
#pragma unroll
        for (int c = 0; c < HID; ++c)
            acc[c] += xv.x * wk[c] + xv.y * wk[HID + c] +
                      xv.z * wk[2 * HID + c] + xv.w * wk[3 * HID + c];
    }
    float di = dinv[r];
    uint pk[HID / 2];
#pragma unroll
    for (int q = 0; q < HID / 2; ++q)
        pk[q] = (uint)f2bf(di * acc[2 * q]) | ((uint)f2bf(di * acc[2 * q + 1]) << 16);
    uint4* gv = (uint4*)(g + (size_t)r * HID);
    gv[0] = make_uint4(pk[0], pk[1], pk[2], pk[3]);
    gv[1] = make_uint4(pk[4], pk[5], pk[6], pk[7]);
}

// ======= layer-1 gather:  g1 = dinv .* relu(dinv.*(Σ w g_src + g_i) + b1) ===
__global__ __launch_bounds__(256) void agg1_k(const ushort* __restrict__ g,
                                              const float* __restrict__ dinv,
                                              const int* __restrict__ off,
                                              const uint* __restrict__ fin,
                                              const float* __restrict__ b1,
                                              ushort* __restrict__ g1, int n) {
    int tid = blockIdx.x * 256 + threadIdx.x;
    int i = tid >> 4;
    if (i >= n) return;
    int lane = tid & 15;
    float acc0 = bf2f(g[(size_t)i * HID + lane]);   // self-loop term
    float acc1 = 0.f, acc2 = 0.f, acc3 = 0.f;
    int p = off[i], e = off[i + 1];
    for (; p + 3 < e; p += 4) {
        uint a = fin[p], b = fin[p + 1], c = fin[p + 2], d = fin[p + 3];
        acc0 += wdec(a) * bf2f(g[(size_t)(a & 0x1FFFFu) * HID + lane]);
        acc1 += wdec(b) * bf2f(g[(size_t)(b & 0x1FFFFu) * HID + lane]);
        acc2 += wdec(c) * bf2f(g[(size_t)(c & 0x1FFFFu) * HID + lane]);
        acc3 += wdec(d) * bf2f(g[(size_t)(d & 0x1FFFFu) * HID + lane]);
    }
    for (; p < e; ++p) {
        uint a = fin[p];
        acc0 += wdec(a) * bf2f(g[(size_t)(a & 0x1FFFFu) * HID + lane]);
    }
    float di = dinv[i];
    float v = di * ((acc0 + acc1) + (acc2 + acc3));
    v = fmaxf(v + b1[lane], 0.f);
    g1[(size_t)i * HID + lane] = f2bf(di * v);
}

// === layer-2 gather fused with W2-matvec + log_softmax (no agg2 roundtrip) ==
__global__ __launch_bounds__(256) void agg2out_k(const ushort* __restrict__ g1,
                                                 const float* __restrict__ dinv,
                                                 const int* __restrict__ off,
                                                 const uint* __restrict__ fin,
                                                 const float* __restrict__ W2,
                                                 const float* __restrict__ b2,
                                                 float* __restrict__ out, int n) {
    __shared__ float w2s[HID * CLS];
    __shared__ float b2s[CLS];
    for (int q = threadIdx.x; q < HID * CLS; q += 256) w2s[q] = W2[q];
    if (threadIdx.x < CLS) b2s[threadIdx.x] = b2[threadIdx.x];
    __syncthreads();
    int tid = blockIdx.x * 256 + threadIdx.x;
    int i = tid >> 4;
    if (i >= n) return;      // whole 16-lane group exits together
    int lane = tid & 15;
    float acc0 = bf2f(g1[(size_t)i * HID + lane]);
    float acc1 = 0.f, acc2 = 0.f, acc3 = 0.f;
    int p = off[i], e = off[i + 1];
    for (; p + 3 < e; p += 4) {
        uint a = fin[p], b = fin[p + 1], c = fin[p + 2], d = fin[p + 3];
        acc0 += wdec(a) * bf2f(g1[(size_t)(a & 0x1FFFFu) * HID + lane]);
        acc1 += wdec(b) * bf2f(g1[(size_t)(b & 0x1FFFFu) * HID + lane]);
        acc2 += wdec(c) * bf2f(g1[(size_t)(c & 0x1FFFFu) * HID + lane]);
        acc3 += wdec(d) * bf2f(g1[(size_t)(d & 0x1FFFFu) * HID + lane]);
    }
    for (; p < e; ++p) {
        uint a = fin[p];
        acc0 += wdec(a) * bf2f(g1[(size_t)(a & 0x1FFFFu) * HID + lane]);
    }
    float v2 = dinv[i] * ((acc0 + acc1) + (acc2 + acc3));   // agg2[i][lane]
    // transpose within the 16-lane group: a[k] = agg2[i][k]
    float a[HID];
#pragma unroll
    for (int k = 0; k < HID; ++k) a[k] = __shfl(v2, k, 16);
    // z[c] for c = lane, lane+16, (lane<8: lane+32)
    float z0 = b2s[lane], z1 = b2s[lane + 16];
    float z2 = (lane < 8) ? b2s[lane + 32] : -1e30f;
#pragma unroll
    for (int k = 0; k < HID; ++k) {
        float ak = a[k];
        z0 += ak * w2s[k * CLS + lane];
        z1 += ak * w2s[k * CLS + lane + 16];
        if (lane < 8) z2 += ak * w2s[k * CLS + lane + 32];
    }
    float m = fmaxf(z0, fmaxf(z1, z2));
#pragma unroll
    for (int d = 1; d < 16; d <<= 1) m = fmaxf(m, __shfl_xor(m, d, 16));
    float s = __expf(z0 - m) + __expf(z1 - m) + ((lane < 8) ? __expf(z2 - m) : 0.f);
#pragma unroll
    for (int d = 1; d < 16; d <<= 1) s += __shfl_xor(s, d, 16);
    float l = __logf(s) + m;
    float* o = out + (size_t)i * CLS;
    o[lane] = z0 - l;
    o[lane + 16] = z1 - l;
    if (lane < 8) o[lane + 32] = z2 - l;
}

extern "C" void kernel_launch(void* const* d_in, const int* in_sizes, int n_in,
                              void* d_out, int out_size, void* d_ws, size_t ws_size,
                              hipStream_t stream) {
    const float* x  = (const float*)d_in[0];
    const float* ew = (const float*)d_in[1];
    const float* W1 = (const float*)d_in[2];
    const float* b1 = (const float*)d_in[3];
    const float* W2 = (const float*)d_in[4];
    const float* b2 = (const float*)d_in[5];
    const int*   ei = (const int*)d_in[6];

    int n = in_sizes[0] / FIN;   // 100000
    int E = in_sizes[1];         // 3200000
    const int* row = ei;
    const int* col = ei + E;

    int NB   = (n + 127) >> 7;            // 782 buckets of 128 nodes
    int NN   = NB * 128;                  // padded node count
    int ABLK = (E + TILE - 1) / TILE;     // 800 bucketize blocks
    int M1   = NB * ABLK;                 // per-(bucket,block) count matrix

    // workspace layout (4B units), 16B-align the vector regions
    size_t o = 0;
    int*   bcnt  = (int*)d_ws + o;  o += M1;
    int*   sbcnt = (int*)d_ws + o;  o += M1;
    int*   bsum  = (int*)d_ws + o;  o += 1024;
    int*   off   = (int*)d_ws + o;  o += (size_t)NN + 1;
    float* dinv  = (float*)((int*)d_ws + o); o += NN;
    uint*  fin   = (uint*)((int*)d_ws + o);  o += E;
    o = (o + 3) & ~(size_t)3;             // 16B align
    int2*  bpack = (int2*)((int*)d_ws + o);  // E int2 (dead after seg_build)
    // aliases into dead bpack region (16B aligned):
    ushort* g    = (ushort*)bpack;                 // 16n bf16
    ushort* g1   = g + (size_t)16 * n;             // 16n bf16

    float* outp = (float*)d_out;

    dim3 b(256);
    int G1 = (M1 + 1023) / 1024;

    // pass A: bucketize (LDS atomics only)
    bk_count_k<<<ABLK, b, 0, stream>>>(col, bcnt, E, NB, ABLK);
    scan1_k<<<G1, b, 0, stream>>>(bcnt, bsum, M1);
    scan2p_k<<<1, b, 0, stream>>>(bsum, G1);
    scan3_k<<<G1, b, 0, stream>>>(bcnt, bsum, sbcnt, M1);
    bk_scatter_k<<<ABLK, b, 0, stream>>>(row, col, ew, sbcnt, bpack, E, NB, ABLK);

    // pass B: single fused kernel (count + local scan + dinv + place)
    seg_build_k<<<NB, b, 0, stream>>>(bpack, sbcnt, off, dinv, fin, E, NB, ABLK, NN);

    // dense pipeline
    gemm1_k<<<(n + 255) / 256, b, 0, stream>>>(x, W1, dinv, g, n);
    int gnodes16 = (n * HID + 255) / 256;
    agg1_k<<<gnodes16, b, 0, stream>>>(g, dinv, off, fin, b1, g1, n);
    agg2out_k<<<gnodes16, b, 0, stream>>>(g1, dinv, off, fin, W2, b2, outp, n);
}